// Round 1
// 719.956 us; speedup vs baseline: 1.0865x; 1.0865x over previous
//
#include <hip/hip_runtime.h>
#include <hip/hip_bf16.h>

#define N_USERS 100000
#define N_ITEMS 150000
#define N_NODES 250000
#define N_EDGES 4000000
#define DIM     64
#define N_ELEM  (N_NODES * DIM)      // 16,000,000
#define U_ELEM  (N_USERS * DIM)      //  6,400,000
#define BSHIFT  8
#define NBUCKET ((N_NODES + (1 << BSHIFT) - 1) >> BSHIFT)  // 977
#define NB_HIST 256
#define CHUNK   (N_EDGES / NB_HIST)  // 15625 (exact)

// ---------------- dtype probe (flag=1 -> bf16 inputs, 0 -> fp32) ----------------
__global__ void probe_dtype(const unsigned short* __restrict__ ue, int* __restrict__ flag) {
    int lane = threadIdx.x;   // 64 threads
    int bad = 0;
    #pragma unroll
    for (int k = 0; k < 8; ++k) {
        unsigned int b = ((unsigned int)ue[lane * 8 + k]) << 16;
        float f = fabsf(__uint_as_float(b));
        if (!(f < 1.0f)) bad = 1;
    }
    unsigned long long m = __ballot(bad);
    if (lane == 0) flag[0] = (m == 0ULL) ? 1 : 0;
}

// ---- stage 1: per-chunk LDS bucket histogram -> M[block][bucket] ----
__global__ void hist_bucket(const int* __restrict__ dst, int* __restrict__ M) {
    __shared__ int h[NBUCKET];
    for (int b = threadIdx.x; b < NBUCKET; b += blockDim.x) h[b] = 0;
    __syncthreads();
    int base = blockIdx.x * CHUNK;
    for (int i = threadIdx.x; i < CHUNK; i += blockDim.x) {
        int e = base + i;
        if (e < N_EDGES) atomicAdd(&h[dst[e] >> BSHIFT], 1);
    }
    __syncthreads();
    for (int b = threadIdx.x; b < NBUCKET; b += blockDim.x)
        M[blockIdx.x * NBUCKET + b] = h[b];
}

// ---- stage 2: single block: bucket bases + per-(block,bucket) bases ----
__global__ void scan_small(int* __restrict__ M, int* __restrict__ bbase,
                           int* __restrict__ row_ptr) {
    __shared__ int sh[1024];
    int b = threadIdx.x;
    int tot = 0;
    if (b < NBUCKET)
        for (int k = 0; k < NB_HIST; ++k) tot += M[k * NBUCKET + b];
    sh[b] = (b < NBUCKET) ? tot : 0;
    __syncthreads();
    for (int off = 1; off < 1024; off <<= 1) {
        int t = (b >= off) ? sh[b - off] : 0;
        __syncthreads();
        sh[b] += t;
        __syncthreads();
    }
    if (b < NBUCKET) {
        int run = sh[b] - tot;             // exclusive bucket base
        bbase[b] = run;
        for (int k = 0; k < NB_HIST; ++k) {
            int t = M[k * NBUCKET + b];
            M[k * NBUCKET + b] = run;      // deterministic base for (block k, bucket b)
            run += t;
        }
    }
    if (b == 0) { bbase[NBUCKET] = N_EDGES; row_ptr[N_NODES] = N_EDGES; }
}

// ---- stage 3: deterministic bucket binning with LDS cursors ----
__global__ void bin_scatter(const int* __restrict__ src, const int* __restrict__ dst,
                            const void* __restrict__ valsv, const int* __restrict__ flag,
                            const int* __restrict__ M, int2* __restrict__ aux) {
    __shared__ int cur[NBUCKET];
    for (int b = threadIdx.x; b < NBUCKET; b += blockDim.x)
        cur[b] = M[blockIdx.x * NBUCKET + b];
    __syncthreads();
    const int isbf = *flag;
    int base = blockIdx.x * CHUNK;
    for (int i = threadIdx.x; i < CHUNK; i += blockDim.x) {
        int e = base + i;
        if (e >= N_EDGES) break;
        int d = dst[e];
        int pos = atomicAdd(&cur[d >> BSHIFT], 1);   // LDS atomic, block-local
        float v = isbf ? __bfloat162float(((const __hip_bfloat16*)valsv)[e])
                       : ((const float*)valsv)[e];
        int2 r;
        r.x = src[e] | ((d & ((1 << BSHIFT) - 1)) << 18);  // src<2^18, dstlo in bits 18..25
        r.y = __float_as_int(v);
        aux[pos] = r;
    }
}

// ---- stage 4: one block per bucket: row_ptr slice + packed sedge, all L2-local ----
__global__ void bucket_csr(const int* __restrict__ bbase, const int2* __restrict__ aux,
                           int* __restrict__ row_ptr, int2* __restrict__ sedge) {
    __shared__ int h[256];
    __shared__ int c[256];
    int b  = blockIdx.x;
    int n0 = b << BSHIFT;
    int nd = N_NODES - n0; if (nd > 256) nd = 256;
    int lo = bbase[b], hi = bbase[b + 1];
    int t = threadIdx.x;
    h[t] = 0;
    __syncthreads();
    for (int e = lo + t; e < hi; e += blockDim.x)
        atomicAdd(&h[(aux[e].x >> 18) & 255], 1);
    __syncthreads();
    int v = h[t];
    c[t] = v;
    __syncthreads();
    for (int off = 1; off < 256; off <<= 1) {
        int u = (t >= off) ? c[t - off] : 0;
        __syncthreads();
        c[t] += u;
        __syncthreads();
    }
    int gbase = lo + c[t] - v;            // exclusive prefix + bucket base
    if (t < nd) row_ptr[n0 + t] = gbase;
    c[t] = gbase;                         // reuse as cursor
    __syncthreads();
    for (int e = lo + t; e < hi; e += blockDim.x) {
        int2 r = aux[e];
        int pos = atomicAdd(&c[(r.x >> 18) & 255], 1);
        int2 o; o.x = r.x & 0x3FFFF; o.y = r.y;
        sedge[pos] = o;
    }
}

// ---------------- init: x0(bf16) = concat(user,item); T2 also seeds out ----------------
__global__ void init_kernel(const void* __restrict__ uev, const void* __restrict__ iev,
                            const int* __restrict__ flag,
                            __hip_bfloat16* __restrict__ x,
                            void* __restrict__ outacc) {  // T2 only (may be null)
    int i = blockIdx.x * blockDim.x + threadIdx.x;
    if (i >= N_ELEM) return;
    const int isbf = *flag;
    float v;
    if (i < U_ELEM) {
        v = isbf ? __bfloat162float(((const __hip_bfloat16*)uev)[i]) : ((const float*)uev)[i];
    } else {
        int j = i - U_ELEM;
        v = isbf ? __bfloat162float(((const __hip_bfloat16*)iev)[j]) : ((const float*)iev)[j];
    }
    x[i] = __float2bfloat16(v);
    if (outacc) {
        if (isbf) ((__hip_bfloat16*)outacc)[i] = __float2bfloat16(0.25f * v);
        else      ((float*)outacc)[i]          = 0.25f * v;
    }
}

// ---------------- bf16 helpers (bit-level, RNE pack) ----------------
__device__ __forceinline__ float bflo(unsigned int u) { return __uint_as_float(u << 16); }
__device__ __forceinline__ float bfhi(unsigned int u) { return __uint_as_float(u & 0xffff0000u); }
__device__ __forceinline__ unsigned int bfr(float f) {   // f32 -> bf16 bits, round-nearest-even
    unsigned int u = __float_as_uint(f);
    return (u + 0x7fffu + ((u >> 16) & 1u)) >> 16;
}
__device__ __forceinline__ unsigned int pk(float a, float b) {  // two bf16 packed, a in low half
    return bfr(a) | (bfr(b) << 16);
}

// ---------------- CSR SpMM: one wave per dst node ----------------
// Lane split: g = lane>>4 (edge slot 0..3), q = lane&15 (dims q*4..q*4+3).
// Each wave step: 4 edges in flight, each lane gathers 8B (4 bf16 dims) of its
// slot's src row -> 4x memory-level parallelism and 1/4 the issue slots per edge
// vs the old 1-edge-per-step layout. Cross-slot reduce: shfl_xor 16 & 32.
// MODE 0: T1 mid   -> xn = bf16(s)
// MODE 1: T1 last  -> out = 0.25*(x0+x1+x2+s)
// MODE 2: T2 mid   -> xn = bf16(s); out += 0.25*s (RMW)
// MODE 3: T2 last  -> out += 0.25*s (RMW)
template <int MODE>
__global__ void spmm_csr(const int* __restrict__ row_ptr,
                         const int2* __restrict__ sedge,
                         const __hip_bfloat16* __restrict__ x,
                         __hip_bfloat16* __restrict__ xn,
                         const __hip_bfloat16* __restrict__ p0,
                         const __hip_bfloat16* __restrict__ p1,
                         void* __restrict__ outv,
                         const int* __restrict__ flag) {
    int lane = threadIdx.x & 63;
    int g = lane >> 4;          // edge slot
    int q = lane & 15;          // dim quad: dims q*4 .. q*4+3
    int w = (blockIdx.x * blockDim.x + threadIdx.x) >> 6;
    if (w >= N_NODES) return;
    int beg = row_ptr[w], end = row_ptr[w + 1];

    const uint2* xq = (const uint2*)x;   // 8B = 4 bf16 dims; row stride 16 uint2
    float s0 = 0.f, s1 = 0.f, s2 = 0.f, s3 = 0.f;
    float t0 = 0.f, t1 = 0.f, t2 = 0.f, t3 = 0.f;

    int e0 = beg;
    // main: 2 quads (8 edges) per iteration, 2 gathers in flight per lane
    for (; e0 + 8 <= end; e0 += 8) {
        int2 ra = sedge[e0 + g];
        int2 rb = sedge[e0 + 4 + g];
        uint2 va = xq[(size_t)ra.x * 16 + q];
        uint2 vb = xq[(size_t)rb.x * 16 + q];
        float wa = __int_as_float(ra.y), wb = __int_as_float(rb.y);
        s0 += wa * bflo(va.x); s1 += wa * bfhi(va.x);
        s2 += wa * bflo(va.y); s3 += wa * bfhi(va.y);
        t0 += wb * bflo(vb.x); t1 += wb * bfhi(vb.x);
        t2 += wb * bflo(vb.y); t3 += wb * bfhi(vb.y);
    }
    // tail: up to 2 predicated quads (invalid slots get weight 0, clamped safe load)
    for (; e0 < end; e0 += 4) {
        int ee = e0 + g;
        int2 r = sedge[(ee < end) ? ee : (end - 1)];
        float wv = (ee < end) ? __int_as_float(r.y) : 0.f;
        uint2 v = xq[(size_t)r.x * 16 + q];
        s0 += wv * bflo(v.x); s1 += wv * bfhi(v.x);
        s2 += wv * bflo(v.y); s3 += wv * bfhi(v.y);
    }
    s0 += t0; s1 += t1; s2 += t2; s3 += t3;

    // reduce across the 4 edge slots (lanes q, q+16, q+32, q+48)
    s0 += __shfl_xor(s0, 16); s1 += __shfl_xor(s1, 16);
    s2 += __shfl_xor(s2, 16); s3 += __shfl_xor(s3, 16);
    s0 += __shfl_xor(s0, 32); s1 += __shfl_xor(s1, 32);
    s2 += __shfl_xor(s2, 32); s3 += __shfl_xor(s3, 32);

    if (g != 0) return;                  // 16 lanes carry the row (128B store)
    size_t oq = (size_t)w * 16 + q;      // uint2/float4 index for dims q*4..q*4+3

    if (MODE == 0) {
        uint2 pv; pv.x = pk(s0, s1); pv.y = pk(s2, s3);
        ((uint2*)xn)[oq] = pv;
    } else if (MODE == 1) {
        uint2 a = ((const uint2*)p0)[oq];
        uint2 b = ((const uint2*)p1)[oq];
        uint2 c = ((const uint2*)x)[oq];          // x == x2 here
        float r0 = 0.25f * (s0 + bflo(a.x) + bflo(b.x) + bflo(c.x));
        float r1 = 0.25f * (s1 + bfhi(a.x) + bfhi(b.x) + bfhi(c.x));
        float r2 = 0.25f * (s2 + bflo(a.y) + bflo(b.y) + bflo(c.y));
        float r3 = 0.25f * (s3 + bfhi(a.y) + bfhi(b.y) + bfhi(c.y));
        if (*flag) {
            uint2 pv; pv.x = pk(r0, r1); pv.y = pk(r2, r3);
            ((uint2*)outv)[oq] = pv;
        } else {
            float4 f; f.x = r0; f.y = r1; f.z = r2; f.w = r3;
            ((float4*)outv)[oq] = f;
        }
    } else if (MODE == 2) {
        uint2 pv; pv.x = pk(s0, s1); pv.y = pk(s2, s3);
        ((uint2*)xn)[oq] = pv;
        if (*flag) {
            uint2 ov = ((uint2*)outv)[oq];
            float r0 = bflo(ov.x) + 0.25f * s0;
            float r1 = bfhi(ov.x) + 0.25f * s1;
            float r2 = bflo(ov.y) + 0.25f * s2;
            float r3 = bfhi(ov.y) + 0.25f * s3;
            uint2 nv; nv.x = pk(r0, r1); nv.y = pk(r2, r3);
            ((uint2*)outv)[oq] = nv;
        } else {
            float4 ov = ((float4*)outv)[oq];
            ov.x += 0.25f * s0; ov.y += 0.25f * s1;
            ov.z += 0.25f * s2; ov.w += 0.25f * s3;
            ((float4*)outv)[oq] = ov;
        }
    } else {
        if (*flag) {
            uint2 ov = ((uint2*)outv)[oq];
            float r0 = bflo(ov.x) + 0.25f * s0;
            float r1 = bfhi(ov.x) + 0.25f * s1;
            float r2 = bflo(ov.y) + 0.25f * s2;
            float r3 = bfhi(ov.y) + 0.25f * s3;
            uint2 nv; nv.x = pk(r0, r1); nv.y = pk(r2, r3);
            ((uint2*)outv)[oq] = nv;
        } else {
            float4 ov = ((float4*)outv)[oq];
            ov.x += 0.25f * s0; ov.y += 0.25f * s1;
            ov.z += 0.25f * s2; ov.w += 0.25f * s3;
            ((float4*)outv)[oq] = ov;
        }
    }
}

// ---------------- host ----------------
static inline size_t align256(size_t x) { return (x + 255) & ~(size_t)255; }

extern "C" void kernel_launch(void* const* d_in, const int* in_sizes, int n_in,
                              void* d_out, int out_size, void* d_ws, size_t ws_size,
                              hipStream_t stream) {
    const int* es = (const int*)d_in[3];
    const int* ed = (const int*)d_in[4];

    char* wsb = (char*)d_ws;
    size_t off = 0;
    int*  flag    = (int*)wsb;               off = align256(off + sizeof(int));
    int*  M       = (int*)(wsb + off);       off = align256(off + (size_t)NB_HIST * NBUCKET * 4);
    int*  bbase   = (int*)(wsb + off);       off = align256(off + (size_t)(NBUCKET + 1) * 4);
    int*  row_ptr = (int*)(wsb + off);       off = align256(off + (size_t)(N_NODES + 1) * 4);
    int2* sedge   = (int2*)(wsb + off);      off = align256(off + (size_t)N_EDGES * 8);
    size_t z_off = off;
    // aux (32 MB) aliases x0: bucket_csr consumes aux before init writes x0.
    int2* aux = (int2*)(wsb + z_off);

    const size_t bfbuf = (size_t)N_ELEM * sizeof(__hip_bfloat16); // 32 MB

    const int eb = 256;
    const int egrid = (N_ELEM + eb - 1) / eb;
    const int sgrid = (N_NODES + 3) / 4;                  // 62500 blocks, 4 waves each

    // ---- build: probe + deterministic two-pass binning (no global atomics) ----
    probe_dtype<<<1, 64, 0, stream>>>((const unsigned short*)d_in[0], flag);
    hist_bucket<<<NB_HIST, eb, 0, stream>>>(ed, M);
    scan_small<<<1, 1024, 0, stream>>>(M, bbase, row_ptr);
    bin_scatter<<<NB_HIST, eb, 0, stream>>>(es, ed, d_in[2], flag, M, aux);
    bucket_csr<<<NBUCKET, eb, 0, stream>>>(bbase, aux, row_ptr, sedge);

    size_t need_t1 = z_off + 3 * bfbuf;   // ~130 MB

    if (ws_size >= need_t1) {
        // T1: bf16 x0,x1,x2; last spmm fuses the 4-term average into d_out
        __hip_bfloat16* x0 = (__hip_bfloat16*)(wsb + z_off);
        __hip_bfloat16* x1 = x0 + N_ELEM;
        __hip_bfloat16* x2 = x1 + N_ELEM;
        init_kernel<<<egrid, eb, 0, stream>>>(d_in[0], d_in[1], flag, x0, nullptr);
        spmm_csr<0><<<sgrid, eb, 0, stream>>>(row_ptr, sedge, x0, x1, nullptr, nullptr, nullptr, flag);
        spmm_csr<0><<<sgrid, eb, 0, stream>>>(row_ptr, sedge, x1, x2, nullptr, nullptr, nullptr, flag);
        spmm_csr<1><<<sgrid, eb, 0, stream>>>(row_ptr, sedge, x2, nullptr, x0, x1, d_out, flag);
    } else {
        // T2: bf16 x, xn; accumulate into d_out (RMW)
        __hip_bfloat16* x  = (__hip_bfloat16*)(wsb + z_off);
        __hip_bfloat16* xn = x + N_ELEM;
        init_kernel<<<egrid, eb, 0, stream>>>(d_in[0], d_in[1], flag, x, d_out);
        spmm_csr<2><<<sgrid, eb, 0, stream>>>(row_ptr, sedge, x,  xn, nullptr, nullptr, d_out, flag);
        spmm_csr<2><<<sgrid, eb, 0, stream>>>(row_ptr, sedge, xn, x,  nullptr, nullptr, d_out, flag);
        spmm_csr<3><<<sgrid, eb, 0, stream>>>(row_ptr, sedge, x,  nullptr, nullptr, nullptr, d_out, flag);
    }
}

// Round 2
// 642.859 us; speedup vs baseline: 1.2168x; 1.1199x over previous
//
#include <hip/hip_runtime.h>
#include <hip/hip_bf16.h>

#define N_USERS 100000
#define N_ITEMS 150000
#define N_NODES 250000
#define N_EDGES 4000000
#define DIM     64
#define N_ELEM  (N_NODES * DIM)      // 16,000,000
#define U_ELEM  (N_USERS * DIM)      //  6,400,000
#define BSHIFT  8
#define NBUCKET ((N_NODES + (1 << BSHIFT) - 1) >> BSHIFT)  // 977
#define NB_HIST 256
#define CHUNK   (N_EDGES / NB_HIST)  // 15625 (exact)

// ---------------- bf16 helpers (bit-level, RNE pack) ----------------
__device__ __forceinline__ float bflo(unsigned int u) { return __uint_as_float(u << 16); }
__device__ __forceinline__ float bfhi(unsigned int u) { return __uint_as_float(u & 0xffff0000u); }
__device__ __forceinline__ unsigned int bfr(float f) {   // f32 -> bf16 bits, round-nearest-even
    unsigned int u = __float_as_uint(f);
    return (u + 0x7fffu + ((u >> 16) & 1u)) >> 16;
}
__device__ __forceinline__ unsigned int pk(float a, float b) {  // two bf16 packed, a in low half
    return bfr(a) | (bfr(b) << 16);
}

// ---------------- dtype probe (flag=1 -> bf16 inputs, 0 -> fp32) ----------------
__global__ void probe_dtype(const unsigned short* __restrict__ ue, int* __restrict__ flag) {
    int lane = threadIdx.x;   // 64 threads
    int bad = 0;
    #pragma unroll
    for (int k = 0; k < 8; ++k) {
        unsigned int b = ((unsigned int)ue[lane * 8 + k]) << 16;
        float f = fabsf(__uint_as_float(b));
        if (!(f < 1.0f)) bad = 1;
    }
    unsigned long long m = __ballot(bad);
    if (lane == 0) flag[0] = (m == 0ULL) ? 1 : 0;
}

// ---- stage 1: per-chunk LDS bucket histogram -> M[block][bucket] ----
__global__ void hist_bucket(const int* __restrict__ dst, int* __restrict__ M) {
    __shared__ int h[NBUCKET];
    for (int b = threadIdx.x; b < NBUCKET; b += blockDim.x) h[b] = 0;
    __syncthreads();
    int base = blockIdx.x * CHUNK;
    for (int i = threadIdx.x; i < CHUNK; i += blockDim.x) {
        int e = base + i;
        if (e < N_EDGES) atomicAdd(&h[dst[e] >> BSHIFT], 1);
    }
    __syncthreads();
    for (int b = threadIdx.x; b < NBUCKET; b += blockDim.x)
        M[blockIdx.x * NBUCKET + b] = h[b];
}

// ---- stage 2a: per-bucket column sum over the 256 chunk histograms (1 wave/bucket) ----
__global__ void col_sum(const int* __restrict__ M, int* __restrict__ tot) {
    int lane = threadIdx.x & 63;
    int b = (blockIdx.x * blockDim.x + threadIdx.x) >> 6;
    if (b >= NBUCKET) return;
    int s = 0;
    #pragma unroll
    for (int k = lane; k < NB_HIST; k += 64) s += M[k * NBUCKET + b];
    #pragma unroll
    for (int off = 32; off; off >>= 1) s += __shfl_xor(s, off);
    if (lane == 0) tot[b] = s;
}

// ---- stage 2b: exclusive scan of 977 bucket totals (single small block) ----
__global__ void scan_bbase(const int* __restrict__ tot, int* __restrict__ bbase,
                           int* __restrict__ row_ptr) {
    __shared__ int sh[1024];
    int b = threadIdx.x;
    int v = (b < NBUCKET) ? tot[b] : 0;
    sh[b] = v;
    __syncthreads();
    for (int off = 1; off < 1024; off <<= 1) {
        int t = (b >= off) ? sh[b - off] : 0;
        __syncthreads();
        sh[b] += t;
        __syncthreads();
    }
    if (b < NBUCKET) bbase[b] = sh[b] - v;     // exclusive
    if (b == 0) { bbase[NBUCKET] = N_EDGES; row_ptr[N_NODES] = N_EDGES; }
}

// ---- stage 2c: per-(chunk,bucket) deterministic bases: 1 wave per bucket ----
// M[k][b] <- bbase[b] + sum_{k'<k} M_old[k'][b]
__global__ void row_base(int* __restrict__ M, const int* __restrict__ bbase) {
    int lane = threadIdx.x & 63;
    int b = (blockIdx.x * blockDim.x + threadIdx.x) >> 6;
    if (b >= NBUCKET) return;
    int k0 = lane * 4;                         // 4 consecutive chunks per lane
    int v0 = M[(k0 + 0) * NBUCKET + b];
    int v1 = M[(k0 + 1) * NBUCKET + b];
    int v2 = M[(k0 + 2) * NBUCKET + b];
    int v3 = M[(k0 + 3) * NBUCKET + b];
    int s = v0 + v1 + v2 + v3;
    int p = s;
    #pragma unroll
    for (int off = 1; off < 64; off <<= 1) {
        int t = __shfl_up(p, off);
        if (lane >= off) p += t;
    }
    int run = bbase[b] + p - s;                // exclusive prefix across lanes
    M[(k0 + 0) * NBUCKET + b] = run; run += v0;
    M[(k0 + 1) * NBUCKET + b] = run; run += v1;
    M[(k0 + 2) * NBUCKET + b] = run; run += v2;
    M[(k0 + 3) * NBUCKET + b] = run;
}

// ---- stage 3: deterministic bucket binning with LDS cursors ----
__global__ void bin_scatter(const int* __restrict__ src, const int* __restrict__ dst,
                            const void* __restrict__ valsv, const int* __restrict__ flag,
                            const int* __restrict__ M, int2* __restrict__ aux) {
    __shared__ int cur[NBUCKET];
    for (int b = threadIdx.x; b < NBUCKET; b += blockDim.x)
        cur[b] = M[blockIdx.x * NBUCKET + b];
    __syncthreads();
    const int isbf = *flag;
    int base = blockIdx.x * CHUNK;
    for (int i = threadIdx.x; i < CHUNK; i += blockDim.x) {
        int e = base + i;
        if (e >= N_EDGES) break;
        int d = dst[e];
        int pos = atomicAdd(&cur[d >> BSHIFT], 1);   // LDS atomic, block-local
        float v = isbf ? __bfloat162float(((const __hip_bfloat16*)valsv)[e])
                       : ((const float*)valsv)[e];
        int2 r;
        r.x = src[e] | ((d & ((1 << BSHIFT) - 1)) << 18);  // src<2^18, dstlo in bits 18..25
        r.y = __float_as_int(v);
        aux[pos] = r;
    }
}

// ---- stage 4: one block per bucket: row_ptr slice + packed sedge, all L2-local ----
__global__ void bucket_csr(const int* __restrict__ bbase, const int2* __restrict__ aux,
                           int* __restrict__ row_ptr, int2* __restrict__ sedge) {
    __shared__ int h[256];
    __shared__ int c[256];
    int b  = blockIdx.x;
    int n0 = b << BSHIFT;
    int nd = N_NODES - n0; if (nd > 256) nd = 256;
    int lo = bbase[b], hi = bbase[b + 1];
    int t = threadIdx.x;
    h[t] = 0;
    __syncthreads();
    for (int e = lo + t; e < hi; e += blockDim.x)
        atomicAdd(&h[(aux[e].x >> 18) & 255], 1);
    __syncthreads();
    int v = h[t];
    c[t] = v;
    __syncthreads();
    for (int off = 1; off < 256; off <<= 1) {
        int u = (t >= off) ? c[t - off] : 0;
        __syncthreads();
        c[t] += u;
        __syncthreads();
    }
    int gbase = lo + c[t] - v;            // exclusive prefix + bucket base
    if (t < nd) row_ptr[n0 + t] = gbase;
    c[t] = gbase;                         // reuse as cursor
    __syncthreads();
    for (int e = lo + t; e < hi; e += blockDim.x) {
        int2 r = aux[e];
        int pos = atomicAdd(&c[(r.x >> 18) & 255], 1);
        int2 o; o.x = r.x & 0x3FFFF; o.y = r.y;
        sedge[pos] = o;
    }
}

// ---------------- init: x0(bf16) = concat(user,item); T2 also seeds out ----------------
// vectorized x4: one thread handles 4 consecutive elements (U_ELEM % 4 == 0)
__global__ void init_kernel(const void* __restrict__ uev, const void* __restrict__ iev,
                            const int* __restrict__ flag,
                            __hip_bfloat16* __restrict__ x,
                            void* __restrict__ outacc) {  // T2 only (may be null)
    int i4 = blockIdx.x * blockDim.x + threadIdx.x;
    if (i4 >= N_ELEM / 4) return;
    const int isbf = *flag;
    float v0, v1, v2, v3;
    if (i4 < U_ELEM / 4) {
        if (isbf) {
            uint2 u = ((const uint2*)uev)[i4];
            v0 = bflo(u.x); v1 = bfhi(u.x); v2 = bflo(u.y); v3 = bfhi(u.y);
        } else {
            float4 f = ((const float4*)uev)[i4];
            v0 = f.x; v1 = f.y; v2 = f.z; v3 = f.w;
        }
    } else {
        int j4 = i4 - U_ELEM / 4;
        if (isbf) {
            uint2 u = ((const uint2*)iev)[j4];
            v0 = bflo(u.x); v1 = bfhi(u.x); v2 = bflo(u.y); v3 = bfhi(u.y);
        } else {
            float4 f = ((const float4*)iev)[j4];
            v0 = f.x; v1 = f.y; v2 = f.z; v3 = f.w;
        }
    }
    uint2 pv; pv.x = pk(v0, v1); pv.y = pk(v2, v3);
    ((uint2*)x)[i4] = pv;
    if (outacc) {
        if (isbf) {
            uint2 o; o.x = pk(0.25f * v0, 0.25f * v1); o.y = pk(0.25f * v2, 0.25f * v3);
            ((uint2*)outacc)[i4] = o;
        } else {
            float4 f; f.x = 0.25f * v0; f.y = 0.25f * v1; f.z = 0.25f * v2; f.w = 0.25f * v3;
            ((float4*)outacc)[i4] = f;
        }
    }
}

// ---------------- CSR SpMM: one wave per dst node, 8 edge slots ----------------
// Lane split: g = lane>>3 (edge slot 0..7), q = lane&7 (dims q*8..q*8+7).
// Each wave step covers 8 edges; each lane gathers 16B (8 bf16 dims) of its slot's
// src row. Main loop unrolls 2 steps (16 edges = 16 cache lines in flight issued
// by 2 load instructions before the first waitcnt). Cross-slot reduce: xor 8/16/32.
// MODE 0: T1 mid   -> xn = bf16(s)
// MODE 1: T1 last  -> out = 0.25*(x0+x1+x2+s)
// MODE 2: T2 mid   -> xn = bf16(s); out += 0.25*s (RMW)
// MODE 3: T2 last  -> out += 0.25*s (RMW)
template <int MODE>
__global__ void spmm_csr(const int* __restrict__ row_ptr,
                         const int2* __restrict__ sedge,
                         const __hip_bfloat16* __restrict__ x,
                         __hip_bfloat16* __restrict__ xn,
                         const __hip_bfloat16* __restrict__ p0,
                         const __hip_bfloat16* __restrict__ p1,
                         void* __restrict__ outv,
                         const int* __restrict__ flag) {
    int lane = threadIdx.x & 63;
    int g = lane >> 3;          // edge slot 0..7
    int q = lane & 7;           // dim octet: dims q*8 .. q*8+7
    int w = (blockIdx.x * blockDim.x + threadIdx.x) >> 6;
    if (w >= N_NODES) return;
    int beg = row_ptr[w], end = row_ptr[w + 1];

    const uint4* xo = (const uint4*)x;   // 16B = 8 bf16 dims; row stride 8 uint4
    float s0 = 0.f, s1 = 0.f, s2 = 0.f, s3 = 0.f, s4 = 0.f, s5 = 0.f, s6 = 0.f, s7 = 0.f;
    float t0 = 0.f, t1 = 0.f, t2 = 0.f, t3 = 0.f, t4 = 0.f, t5 = 0.f, t6 = 0.f, t7 = 0.f;

    int e0 = beg;
    // main: 16 edges per iteration, 16 gather lines in flight per wave
    for (; e0 + 16 <= end; e0 += 16) {
        int2 ra = sedge[e0 + g];
        int2 rb = sedge[e0 + 8 + g];
        uint4 va = xo[(size_t)ra.x * 8 + q];
        uint4 vb = xo[(size_t)rb.x * 8 + q];
        float wa = __int_as_float(ra.y), wb = __int_as_float(rb.y);
        s0 += wa * bflo(va.x); s1 += wa * bfhi(va.x);
        s2 += wa * bflo(va.y); s3 += wa * bfhi(va.y);
        s4 += wa * bflo(va.z); s5 += wa * bfhi(va.z);
        s6 += wa * bflo(va.w); s7 += wa * bfhi(va.w);
        t0 += wb * bflo(vb.x); t1 += wb * bfhi(vb.x);
        t2 += wb * bflo(vb.y); t3 += wb * bfhi(vb.y);
        t4 += wb * bflo(vb.z); t5 += wb * bfhi(vb.z);
        t6 += wb * bflo(vb.w); t7 += wb * bfhi(vb.w);
    }
    // tail: up to 2 predicated 8-edge steps (invalid slots get weight 0, clamped load)
    for (; e0 < end; e0 += 8) {
        int ee = e0 + g;
        int2 r = sedge[(ee < end) ? ee : (end - 1)];
        float wv = (ee < end) ? __int_as_float(r.y) : 0.f;
        uint4 v = xo[(size_t)r.x * 8 + q];
        s0 += wv * bflo(v.x); s1 += wv * bfhi(v.x);
        s2 += wv * bflo(v.y); s3 += wv * bfhi(v.y);
        s4 += wv * bflo(v.z); s5 += wv * bfhi(v.z);
        s6 += wv * bflo(v.w); s7 += wv * bfhi(v.w);
    }
    s0 += t0; s1 += t1; s2 += t2; s3 += t3;
    s4 += t4; s5 += t5; s6 += t6; s7 += t7;

    // reduce across the 8 edge slots (lanes q, q+8, ..., q+56)
    s0 += __shfl_xor(s0, 8);  s1 += __shfl_xor(s1, 8);
    s2 += __shfl_xor(s2, 8);  s3 += __shfl_xor(s3, 8);
    s4 += __shfl_xor(s4, 8);  s5 += __shfl_xor(s5, 8);
    s6 += __shfl_xor(s6, 8);  s7 += __shfl_xor(s7, 8);
    s0 += __shfl_xor(s0, 16); s1 += __shfl_xor(s1, 16);
    s2 += __shfl_xor(s2, 16); s3 += __shfl_xor(s3, 16);
    s4 += __shfl_xor(s4, 16); s5 += __shfl_xor(s5, 16);
    s6 += __shfl_xor(s6, 16); s7 += __shfl_xor(s7, 16);
    s0 += __shfl_xor(s0, 32); s1 += __shfl_xor(s1, 32);
    s2 += __shfl_xor(s2, 32); s3 += __shfl_xor(s3, 32);
    s4 += __shfl_xor(s4, 32); s5 += __shfl_xor(s5, 32);
    s6 += __shfl_xor(s6, 32); s7 += __shfl_xor(s7, 32);

    if (g != 0) return;                  // 8 lanes carry the row (128B store)
    size_t oq = (size_t)w * 8 + q;       // uint4 index for dims q*8..q*8+7

    if (MODE == 0) {
        uint4 pv;
        pv.x = pk(s0, s1); pv.y = pk(s2, s3); pv.z = pk(s4, s5); pv.w = pk(s6, s7);
        ((uint4*)xn)[oq] = pv;
    } else if (MODE == 1) {
        uint4 a = ((const uint4*)p0)[oq];
        uint4 b = ((const uint4*)p1)[oq];
        uint4 c = ((const uint4*)x)[oq];          // x == x2 here
        float r0 = 0.25f * (s0 + bflo(a.x) + bflo(b.x) + bflo(c.x));
        float r1 = 0.25f * (s1 + bfhi(a.x) + bfhi(b.x) + bfhi(c.x));
        float r2 = 0.25f * (s2 + bflo(a.y) + bflo(b.y) + bflo(c.y));
        float r3 = 0.25f * (s3 + bfhi(a.y) + bfhi(b.y) + bfhi(c.y));
        float r4 = 0.25f * (s4 + bflo(a.z) + bflo(b.z) + bflo(c.z));
        float r5 = 0.25f * (s5 + bfhi(a.z) + bfhi(b.z) + bfhi(c.z));
        float r6 = 0.25f * (s6 + bflo(a.w) + bflo(b.w) + bflo(c.w));
        float r7 = 0.25f * (s7 + bfhi(a.w) + bfhi(b.w) + bfhi(c.w));
        if (*flag) {
            uint4 pv;
            pv.x = pk(r0, r1); pv.y = pk(r2, r3); pv.z = pk(r4, r5); pv.w = pk(r6, r7);
            ((uint4*)outv)[oq] = pv;
        } else {
            float4 f0; f0.x = r0; f0.y = r1; f0.z = r2; f0.w = r3;
            float4 f1; f1.x = r4; f1.y = r5; f1.z = r6; f1.w = r7;
            ((float4*)outv)[2 * oq]     = f0;
            ((float4*)outv)[2 * oq + 1] = f1;
        }
    } else if (MODE == 2) {
        uint4 pv;
        pv.x = pk(s0, s1); pv.y = pk(s2, s3); pv.z = pk(s4, s5); pv.w = pk(s6, s7);
        ((uint4*)xn)[oq] = pv;
        if (*flag) {
            uint4 ov = ((uint4*)outv)[oq];
            float r0 = bflo(ov.x) + 0.25f * s0;
            float r1 = bfhi(ov.x) + 0.25f * s1;
            float r2 = bflo(ov.y) + 0.25f * s2;
            float r3 = bfhi(ov.y) + 0.25f * s3;
            float r4 = bflo(ov.z) + 0.25f * s4;
            float r5 = bfhi(ov.z) + 0.25f * s5;
            float r6 = bflo(ov.w) + 0.25f * s6;
            float r7 = bfhi(ov.w) + 0.25f * s7;
            uint4 nv;
            nv.x = pk(r0, r1); nv.y = pk(r2, r3); nv.z = pk(r4, r5); nv.w = pk(r6, r7);
            ((uint4*)outv)[oq] = nv;
        } else {
            float4 o0 = ((float4*)outv)[2 * oq];
            float4 o1 = ((float4*)outv)[2 * oq + 1];
            o0.x += 0.25f * s0; o0.y += 0.25f * s1; o0.z += 0.25f * s2; o0.w += 0.25f * s3;
            o1.x += 0.25f * s4; o1.y += 0.25f * s5; o1.z += 0.25f * s6; o1.w += 0.25f * s7;
            ((float4*)outv)[2 * oq]     = o0;
            ((float4*)outv)[2 * oq + 1] = o1;
        }
    } else {
        if (*flag) {
            uint4 ov = ((uint4*)outv)[oq];
            float r0 = bflo(ov.x) + 0.25f * s0;
            float r1 = bfhi(ov.x) + 0.25f * s1;
            float r2 = bflo(ov.y) + 0.25f * s2;
            float r3 = bfhi(ov.y) + 0.25f * s3;
            float r4 = bflo(ov.z) + 0.25f * s4;
            float r5 = bfhi(ov.z) + 0.25f * s5;
            float r6 = bflo(ov.w) + 0.25f * s6;
            float r7 = bfhi(ov.w) + 0.25f * s7;
            uint4 nv;
            nv.x = pk(r0, r1); nv.y = pk(r2, r3); nv.z = pk(r4, r5); nv.w = pk(r6, r7);
            ((uint4*)outv)[oq] = nv;
        } else {
            float4 o0 = ((float4*)outv)[2 * oq];
            float4 o1 = ((float4*)outv)[2 * oq + 1];
            o0.x += 0.25f * s0; o0.y += 0.25f * s1; o0.z += 0.25f * s2; o0.w += 0.25f * s3;
            o1.x += 0.25f * s4; o1.y += 0.25f * s5; o1.z += 0.25f * s6; o1.w += 0.25f * s7;
            ((float4*)outv)[2 * oq]     = o0;
            ((float4*)outv)[2 * oq + 1] = o1;
        }
    }
}

// ---------------- host ----------------
static inline size_t align256(size_t x) { return (x + 255) & ~(size_t)255; }

extern "C" void kernel_launch(void* const* d_in, const int* in_sizes, int n_in,
                              void* d_out, int out_size, void* d_ws, size_t ws_size,
                              hipStream_t stream) {
    const int* es = (const int*)d_in[3];
    const int* ed = (const int*)d_in[4];

    char* wsb = (char*)d_ws;
    size_t off = 0;
    int*  flag    = (int*)wsb;               off = align256(off + sizeof(int));
    int*  M       = (int*)(wsb + off);       off = align256(off + (size_t)NB_HIST * NBUCKET * 4);
    int*  bbase   = (int*)(wsb + off);       off = align256(off + (size_t)(NBUCKET + 1) * 4);
    int*  tot     = (int*)(wsb + off);       off = align256(off + (size_t)NBUCKET * 4);
    int*  row_ptr = (int*)(wsb + off);       off = align256(off + (size_t)(N_NODES + 1) * 4);
    int2* sedge   = (int2*)(wsb + off);      off = align256(off + (size_t)N_EDGES * 8);
    size_t z_off = off;
    // aux (32 MB) aliases x0: bucket_csr consumes aux before init writes x0.
    int2* aux = (int2*)(wsb + z_off);

    const size_t bfbuf = (size_t)N_ELEM * sizeof(__hip_bfloat16); // 32 MB

    const int eb = 256;
    const int egrid = (N_ELEM / 4 + eb - 1) / eb;         // init, x4-vectorized
    const int sgrid = (N_NODES + 3) / 4;                  // 62500 blocks, 4 waves each
    const int wgrid = (NBUCKET + 3) / 4;                  // 1 wave per bucket kernels

    // ---- build: probe + deterministic two-pass binning (no global atomics) ----
    probe_dtype<<<1, 64, 0, stream>>>((const unsigned short*)d_in[0], flag);
    hist_bucket<<<NB_HIST, eb, 0, stream>>>(ed, M);
    col_sum<<<wgrid, eb, 0, stream>>>(M, tot);
    scan_bbase<<<1, 1024, 0, stream>>>(tot, bbase, row_ptr);
    row_base<<<wgrid, eb, 0, stream>>>(M, bbase);
    bin_scatter<<<NB_HIST, eb, 0, stream>>>(es, ed, d_in[2], flag, M, aux);
    bucket_csr<<<NBUCKET, eb, 0, stream>>>(bbase, aux, row_ptr, sedge);

    size_t need_t1 = z_off + 3 * bfbuf;   // ~130 MB

    if (ws_size >= need_t1) {
        // T1: bf16 x0,x1,x2; last spmm fuses the 4-term average into d_out
        __hip_bfloat16* x0 = (__hip_bfloat16*)(wsb + z_off);
        __hip_bfloat16* x1 = x0 + N_ELEM;
        __hip_bfloat16* x2 = x1 + N_ELEM;
        init_kernel<<<egrid, eb, 0, stream>>>(d_in[0], d_in[1], flag, x0, nullptr);
        spmm_csr<0><<<sgrid, eb, 0, stream>>>(row_ptr, sedge, x0, x1, nullptr, nullptr, nullptr, flag);
        spmm_csr<0><<<sgrid, eb, 0, stream>>>(row_ptr, sedge, x1, x2, nullptr, nullptr, nullptr, flag);
        spmm_csr<1><<<sgrid, eb, 0, stream>>>(row_ptr, sedge, x2, nullptr, x0, x1, d_out, flag);
    } else {
        // T2: bf16 x, xn; accumulate into d_out (RMW)
        __hip_bfloat16* x  = (__hip_bfloat16*)(wsb + z_off);
        __hip_bfloat16* xn = x + N_ELEM;
        init_kernel<<<egrid, eb, 0, stream>>>(d_in[0], d_in[1], flag, x, d_out);
        spmm_csr<2><<<sgrid, eb, 0, stream>>>(row_ptr, sedge, x,  xn, nullptr, nullptr, d_out, flag);
        spmm_csr<2><<<sgrid, eb, 0, stream>>>(row_ptr, sedge, xn, x,  nullptr, nullptr, d_out, flag);
        spmm_csr<3><<<sgrid, eb, 0, stream>>>(row_ptr, sedge, x,  nullptr, nullptr, nullptr, d_out, flag);
    }
}

// Round 3
// 637.766 us; speedup vs baseline: 1.2266x; 1.0080x over previous
//
#include <hip/hip_runtime.h>
#include <hip/hip_bf16.h>

#define N_USERS 100000
#define N_ITEMS 150000
#define N_NODES 250000
#define N_EDGES 4000000
#define DIM     64
#define N_ELEM  (N_NODES * DIM)      // 16,000,000
#define U_ELEM  (N_USERS * DIM)      //  6,400,000
#define BSHIFT  8
#define NBUCKET ((N_NODES + (1 << BSHIFT) - 1) >> BSHIFT)  // 977
#define NB_HIST 2048
#define CHUNK   ((N_EDGES + NB_HIST - 1) / NB_HIST)  // 1954
#define KPL     (NB_HIST / 64)       // 32 chunks per lane in row_base/col_sum

// ---------------- bf16 helpers (bit-level, RNE pack) ----------------
__device__ __forceinline__ float bflo(unsigned int u) { return __uint_as_float(u << 16); }
__device__ __forceinline__ float bfhi(unsigned int u) { return __uint_as_float(u & 0xffff0000u); }
__device__ __forceinline__ unsigned int bfr(float f) {   // f32 -> bf16 bits, round-nearest-even
    unsigned int u = __float_as_uint(f);
    return (u + 0x7fffu + ((u >> 16) & 1u)) >> 16;
}
__device__ __forceinline__ unsigned int pk(float a, float b) {  // two bf16 packed, a in low half
    return bfr(a) | (bfr(b) << 16);
}

// ---------------- dtype probe (flag=1 -> bf16 inputs, 0 -> fp32) ----------------
__global__ void probe_dtype(const unsigned short* __restrict__ ue, int* __restrict__ flag) {
    int lane = threadIdx.x;   // 64 threads
    int bad = 0;
    #pragma unroll
    for (int k = 0; k < 8; ++k) {
        unsigned int b = ((unsigned int)ue[lane * 8 + k]) << 16;
        float f = fabsf(__uint_as_float(b));
        if (!(f < 1.0f)) bad = 1;
    }
    unsigned long long m = __ballot(bad);
    if (lane == 0) flag[0] = (m == 0ULL) ? 1 : 0;
}

// ---- stage 1: per-chunk LDS bucket histogram -> M[block][bucket] ----
__global__ void hist_bucket(const int* __restrict__ dst, int* __restrict__ M) {
    __shared__ int h[NBUCKET];
    for (int b = threadIdx.x; b < NBUCKET; b += blockDim.x) h[b] = 0;
    __syncthreads();
    int base = blockIdx.x * CHUNK;
    for (int i = threadIdx.x; i < CHUNK; i += blockDim.x) {
        int e = base + i;
        if (e < N_EDGES) atomicAdd(&h[dst[e] >> BSHIFT], 1);
    }
    __syncthreads();
    for (int b = threadIdx.x; b < NBUCKET; b += blockDim.x)
        M[blockIdx.x * NBUCKET + b] = h[b];
}

// ---- stage 2a: per-bucket column sum over the chunk histograms (1 wave/bucket) ----
__global__ void col_sum(const int* __restrict__ M, int* __restrict__ tot) {
    int lane = threadIdx.x & 63;
    int b = (blockIdx.x * blockDim.x + threadIdx.x) >> 6;
    if (b >= NBUCKET) return;
    int s = 0;
    #pragma unroll 8
    for (int k = lane; k < NB_HIST; k += 64) s += M[k * NBUCKET + b];
    #pragma unroll
    for (int off = 32; off; off >>= 1) s += __shfl_xor(s, off);
    if (lane == 0) tot[b] = s;
}

// ---- stage 2b: exclusive scan of 977 bucket totals (single small block) ----
__global__ void scan_bbase(const int* __restrict__ tot, int* __restrict__ bbase,
                           int* __restrict__ row_ptr) {
    __shared__ int sh[1024];
    int b = threadIdx.x;
    int v = (b < NBUCKET) ? tot[b] : 0;
    sh[b] = v;
    __syncthreads();
    for (int off = 1; off < 1024; off <<= 1) {
        int t = (b >= off) ? sh[b - off] : 0;
        __syncthreads();
        sh[b] += t;
        __syncthreads();
    }
    if (b < NBUCKET) bbase[b] = sh[b] - v;     // exclusive
    if (b == 0) { bbase[NBUCKET] = N_EDGES; row_ptr[N_NODES] = N_EDGES; }
}

// ---- stage 2c: per-(chunk,bucket) deterministic bases: 1 wave per bucket ----
// M[k][b] <- bbase[b] + sum_{k'<k} M_old[k'][b]
__global__ void row_base(int* __restrict__ M, const int* __restrict__ bbase) {
    int lane = threadIdx.x & 63;
    int b = (blockIdx.x * blockDim.x + threadIdx.x) >> 6;
    if (b >= NBUCKET) return;
    int k0 = lane * KPL;                       // KPL consecutive chunks per lane
    int v[KPL];
    int s = 0;
    #pragma unroll
    for (int j = 0; j < KPL; ++j) { v[j] = M[(k0 + j) * NBUCKET + b]; s += v[j]; }
    int p = s;
    #pragma unroll
    for (int off = 1; off < 64; off <<= 1) {
        int t = __shfl_up(p, off);
        if (lane >= off) p += t;
    }
    int run = bbase[b] + p - s;                // exclusive prefix across lanes
    #pragma unroll
    for (int j = 0; j < KPL; ++j) { M[(k0 + j) * NBUCKET + b] = run; run += v[j]; }
}

// ---- stage 3: deterministic bucket binning with LDS cursors ----
__global__ void bin_scatter(const int* __restrict__ src, const int* __restrict__ dst,
                            const void* __restrict__ valsv, const int* __restrict__ flag,
                            const int* __restrict__ M, int2* __restrict__ aux) {
    __shared__ int cur[NBUCKET];
    for (int b = threadIdx.x; b < NBUCKET; b += blockDim.x)
        cur[b] = M[blockIdx.x * NBUCKET + b];
    __syncthreads();
    const int isbf = *flag;
    int base = blockIdx.x * CHUNK;
    for (int i = threadIdx.x; i < CHUNK; i += blockDim.x) {
        int e = base + i;
        if (e >= N_EDGES) break;
        int d = dst[e];
        int pos = atomicAdd(&cur[d >> BSHIFT], 1);   // LDS atomic, block-local
        float v = isbf ? __bfloat162float(((const __hip_bfloat16*)valsv)[e])
                       : ((const float*)valsv)[e];
        int2 r;
        r.x = src[e] | ((d & ((1 << BSHIFT) - 1)) << 18);  // src<2^18, dstlo in bits 18..25
        r.y = __float_as_int(v);
        aux[pos] = r;
    }
}

// ---- stage 4: one block per bucket: row_ptr slice + packed sedge, all L2-local ----
__global__ void bucket_csr(const int* __restrict__ bbase, const int2* __restrict__ aux,
                           int* __restrict__ row_ptr, int2* __restrict__ sedge) {
    __shared__ int h[256];
    __shared__ int c[256];
    int b  = blockIdx.x;
    int n0 = b << BSHIFT;
    int nd = N_NODES - n0; if (nd > 256) nd = 256;
    int lo = bbase[b], hi = bbase[b + 1];
    int t = threadIdx.x;
    h[t] = 0;
    __syncthreads();
    for (int e = lo + t; e < hi; e += blockDim.x)
        atomicAdd(&h[(aux[e].x >> 18) & 255], 1);
    __syncthreads();
    int v = h[t];
    c[t] = v;
    __syncthreads();
    for (int off = 1; off < 256; off <<= 1) {
        int u = (t >= off) ? c[t - off] : 0;
        __syncthreads();
        c[t] += u;
        __syncthreads();
    }
    int gbase = lo + c[t] - v;            // exclusive prefix + bucket base
    if (t < nd) row_ptr[n0 + t] = gbase;
    c[t] = gbase;                         // reuse as cursor
    __syncthreads();
    for (int e = lo + t; e < hi; e += blockDim.x) {
        int2 r = aux[e];
        int pos = atomicAdd(&c[(r.x >> 18) & 255], 1);
        int2 o; o.x = r.x & 0x3FFFF; o.y = r.y;
        sedge[pos] = o;
    }
}

// ---------------- init: x0(bf16) = concat(user,item); T2 also seeds out ----------------
// vectorized x4: one thread handles 4 consecutive elements (U_ELEM % 4 == 0)
__global__ void init_kernel(const void* __restrict__ uev, const void* __restrict__ iev,
                            const int* __restrict__ flag,
                            __hip_bfloat16* __restrict__ x,
                            void* __restrict__ outacc) {  // T2 only (may be null)
    int i4 = blockIdx.x * blockDim.x + threadIdx.x;
    if (i4 >= N_ELEM / 4) return;
    const int isbf = *flag;
    float v0, v1, v2, v3;
    if (i4 < U_ELEM / 4) {
        if (isbf) {
            uint2 u = ((const uint2*)uev)[i4];
            v0 = bflo(u.x); v1 = bfhi(u.x); v2 = bflo(u.y); v3 = bfhi(u.y);
        } else {
            float4 f = ((const float4*)uev)[i4];
            v0 = f.x; v1 = f.y; v2 = f.z; v3 = f.w;
        }
    } else {
        int j4 = i4 - U_ELEM / 4;
        if (isbf) {
            uint2 u = ((const uint2*)iev)[j4];
            v0 = bflo(u.x); v1 = bfhi(u.x); v2 = bflo(u.y); v3 = bfhi(u.y);
        } else {
            float4 f = ((const float4*)iev)[j4];
            v0 = f.x; v1 = f.y; v2 = f.z; v3 = f.w;
        }
    }
    uint2 pv; pv.x = pk(v0, v1); pv.y = pk(v2, v3);
    ((uint2*)x)[i4] = pv;
    if (outacc) {
        if (isbf) {
            uint2 o; o.x = pk(0.25f * v0, 0.25f * v1); o.y = pk(0.25f * v2, 0.25f * v3);
            ((uint2*)outacc)[i4] = o;
        } else {
            float4 f; f.x = 0.25f * v0; f.y = 0.25f * v1; f.z = 0.25f * v2; f.w = 0.25f * v3;
            ((float4*)outacc)[i4] = f;
        }
    }
}

// ---------------- CSR SpMM: one wave per dst node, 8 edge slots ----------------
// Lane split: g = lane>>3 (edge slot 0..7), q = lane&7 (dims q*8..q*8+7).
// Each wave step covers 8 edges; each lane gathers 16B (8 bf16 dims) of its slot's
// src row. Main loop unrolls 2 steps (16 edges = 16 cache lines in flight issued
// by 2 load instructions before the first waitcnt). Cross-slot reduce: xor 8/16/32.
// MODE 0: T1 mid   -> xn = bf16(s)
// MODE 1: T1 last  -> out = 0.25*(x0+x1+x2+s)
// MODE 2: T2 mid   -> xn = bf16(s); out += 0.25*s (RMW)
// MODE 3: T2 last  -> out += 0.25*s (RMW)
template <int MODE>
__global__ void spmm_csr(const int* __restrict__ row_ptr,
                         const int2* __restrict__ sedge,
                         const __hip_bfloat16* __restrict__ x,
                         __hip_bfloat16* __restrict__ xn,
                         const __hip_bfloat16* __restrict__ p0,
                         const __hip_bfloat16* __restrict__ p1,
                         void* __restrict__ outv,
                         const int* __restrict__ flag) {
    int lane = threadIdx.x & 63;
    int g = lane >> 3;          // edge slot 0..7
    int q = lane & 7;           // dim octet: dims q*8 .. q*8+7
    int w = (blockIdx.x * blockDim.x + threadIdx.x) >> 6;
    if (w >= N_NODES) return;
    int beg = row_ptr[w], end = row_ptr[w + 1];

    const uint4* xo = (const uint4*)x;   // 16B = 8 bf16 dims; row stride 8 uint4
    float s0 = 0.f, s1 = 0.f, s2 = 0.f, s3 = 0.f, s4 = 0.f, s5 = 0.f, s6 = 0.f, s7 = 0.f;
    float t0 = 0.f, t1 = 0.f, t2 = 0.f, t3 = 0.f, t4 = 0.f, t5 = 0.f, t6 = 0.f, t7 = 0.f;

    int e0 = beg;
    // main: 16 edges per iteration, 16 gather lines in flight per wave
    for (; e0 + 16 <= end; e0 += 16) {
        int2 ra = sedge[e0 + g];
        int2 rb = sedge[e0 + 8 + g];
        uint4 va = xo[(size_t)ra.x * 8 + q];
        uint4 vb = xo[(size_t)rb.x * 8 + q];
        float wa = __int_as_float(ra.y), wb = __int_as_float(rb.y);
        s0 += wa * bflo(va.x); s1 += wa * bfhi(va.x);
        s2 += wa * bflo(va.y); s3 += wa * bfhi(va.y);
        s4 += wa * bflo(va.z); s5 += wa * bfhi(va.z);
        s6 += wa * bflo(va.w); s7 += wa * bfhi(va.w);
        t0 += wb * bflo(vb.x); t1 += wb * bfhi(vb.x);
        t2 += wb * bflo(vb.y); t3 += wb * bfhi(vb.y);
        t4 += wb * bflo(vb.z); t5 += wb * bfhi(vb.z);
        t6 += wb * bflo(vb.w); t7 += wb * bfhi(vb.w);
    }
    // tail: up to 2 predicated 8-edge steps (invalid slots get weight 0, clamped load)
    for (; e0 < end; e0 += 8) {
        int ee = e0 + g;
        int2 r = sedge[(ee < end) ? ee : (end - 1)];
        float wv = (ee < end) ? __int_as_float(r.y) : 0.f;
        uint4 v = xo[(size_t)r.x * 8 + q];
        s0 += wv * bflo(v.x); s1 += wv * bfhi(v.x);
        s2 += wv * bflo(v.y); s3 += wv * bfhi(v.y);
        s4 += wv * bflo(v.z); s5 += wv * bfhi(v.z);
        s6 += wv * bflo(v.w); s7 += wv * bfhi(v.w);
    }
    s0 += t0; s1 += t1; s2 += t2; s3 += t3;
    s4 += t4; s5 += t5; s6 += t6; s7 += t7;

    // reduce across the 8 edge slots (lanes q, q+8, ..., q+56)
    s0 += __shfl_xor(s0, 8);  s1 += __shfl_xor(s1, 8);
    s2 += __shfl_xor(s2, 8);  s3 += __shfl_xor(s3, 8);
    s4 += __shfl_xor(s4, 8);  s5 += __shfl_xor(s5, 8);
    s6 += __shfl_xor(s6, 8);  s7 += __shfl_xor(s7, 8);
    s0 += __shfl_xor(s0, 16); s1 += __shfl_xor(s1, 16);
    s2 += __shfl_xor(s2, 16); s3 += __shfl_xor(s3, 16);
    s4 += __shfl_xor(s4, 16); s5 += __shfl_xor(s5, 16);
    s6 += __shfl_xor(s6, 16); s7 += __shfl_xor(s7, 16);
    s0 += __shfl_xor(s0, 32); s1 += __shfl_xor(s1, 32);
    s2 += __shfl_xor(s2, 32); s3 += __shfl_xor(s3, 32);
    s4 += __shfl_xor(s4, 32); s5 += __shfl_xor(s5, 32);
    s6 += __shfl_xor(s6, 32); s7 += __shfl_xor(s7, 32);

    if (g != 0) return;                  // 8 lanes carry the row (128B store)
    size_t oq = (size_t)w * 8 + q;       // uint4 index for dims q*8..q*8+7

    if (MODE == 0) {
        uint4 pv;
        pv.x = pk(s0, s1); pv.y = pk(s2, s3); pv.z = pk(s4, s5); pv.w = pk(s6, s7);
        ((uint4*)xn)[oq] = pv;
    } else if (MODE == 1) {
        uint4 a = ((const uint4*)p0)[oq];
        uint4 b = ((const uint4*)p1)[oq];
        uint4 c = ((const uint4*)x)[oq];          // x == x2 here
        float r0 = 0.25f * (s0 + bflo(a.x) + bflo(b.x) + bflo(c.x));
        float r1 = 0.25f * (s1 + bfhi(a.x) + bfhi(b.x) + bfhi(c.x));
        float r2 = 0.25f * (s2 + bflo(a.y) + bflo(b.y) + bflo(c.y));
        float r3 = 0.25f * (s3 + bfhi(a.y) + bfhi(b.y) + bfhi(c.y));
        float r4 = 0.25f * (s4 + bflo(a.z) + bflo(b.z) + bflo(c.z));
        float r5 = 0.25f * (s5 + bfhi(a.z) + bfhi(b.z) + bfhi(c.z));
        float r6 = 0.25f * (s6 + bflo(a.w) + bflo(b.w) + bflo(c.w));
        float r7 = 0.25f * (s7 + bfhi(a.w) + bfhi(b.w) + bfhi(c.w));
        if (*flag) {
            uint4 pv;
            pv.x = pk(r0, r1); pv.y = pk(r2, r3); pv.z = pk(r4, r5); pv.w = pk(r6, r7);
            ((uint4*)outv)[oq] = pv;
        } else {
            float4 f0; f0.x = r0; f0.y = r1; f0.z = r2; f0.w = r3;
            float4 f1; f1.x = r4; f1.y = r5; f1.z = r6; f1.w = r7;
            ((float4*)outv)[2 * oq]     = f0;
            ((float4*)outv)[2 * oq + 1] = f1;
        }
    } else if (MODE == 2) {
        uint4 pv;
        pv.x = pk(s0, s1); pv.y = pk(s2, s3); pv.z = pk(s4, s5); pv.w = pk(s6, s7);
        ((uint4*)xn)[oq] = pv;
        if (*flag) {
            uint4 ov = ((uint4*)outv)[oq];
            float r0 = bflo(ov.x) + 0.25f * s0;
            float r1 = bfhi(ov.x) + 0.25f * s1;
            float r2 = bflo(ov.y) + 0.25f * s2;
            float r3 = bfhi(ov.y) + 0.25f * s3;
            float r4 = bflo(ov.z) + 0.25f * s4;
            float r5 = bfhi(ov.z) + 0.25f * s5;
            float r6 = bflo(ov.w) + 0.25f * s6;
            float r7 = bfhi(ov.w) + 0.25f * s7;
            uint4 nv;
            nv.x = pk(r0, r1); nv.y = pk(r2, r3); nv.z = pk(r4, r5); nv.w = pk(r6, r7);
            ((uint4*)outv)[oq] = nv;
        } else {
            float4 o0 = ((float4*)outv)[2 * oq];
            float4 o1 = ((float4*)outv)[2 * oq + 1];
            o0.x += 0.25f * s0; o0.y += 0.25f * s1; o0.z += 0.25f * s2; o0.w += 0.25f * s3;
            o1.x += 0.25f * s4; o1.y += 0.25f * s5; o1.z += 0.25f * s6; o1.w += 0.25f * s7;
            ((float4*)outv)[2 * oq]     = o0;
            ((float4*)outv)[2 * oq + 1] = o1;
        }
    } else {
        if (*flag) {
            uint4 ov = ((uint4*)outv)[oq];
            float r0 = bflo(ov.x) + 0.25f * s0;
            float r1 = bfhi(ov.x) + 0.25f * s1;
            float r2 = bflo(ov.y) + 0.25f * s2;
            float r3 = bfhi(ov.y) + 0.25f * s3;
            float r4 = bflo(ov.z) + 0.25f * s4;
            float r5 = bfhi(ov.z) + 0.25f * s5;
            float r6 = bflo(ov.w) + 0.25f * s6;
            float r7 = bfhi(ov.w) + 0.25f * s7;
            uint4 nv;
            nv.x = pk(r0, r1); nv.y = pk(r2, r3); nv.z = pk(r4, r5); nv.w = pk(r6, r7);
            ((uint4*)outv)[oq] = nv;
        } else {
            float4 o0 = ((float4*)outv)[2 * oq];
            float4 o1 = ((float4*)outv)[2 * oq + 1];
            o0.x += 0.25f * s0; o0.y += 0.25f * s1; o0.z += 0.25f * s2; o0.w += 0.25f * s3;
            o1.x += 0.25f * s4; o1.y += 0.25f * s5; o1.z += 0.25f * s6; o1.w += 0.25f * s7;
            ((float4*)outv)[2 * oq]     = o0;
            ((float4*)outv)[2 * oq + 1] = o1;
        }
    }
}

// ---------------- host ----------------
static inline size_t align256(size_t x) { return (x + 255) & ~(size_t)255; }

extern "C" void kernel_launch(void* const* d_in, const int* in_sizes, int n_in,
                              void* d_out, int out_size, void* d_ws, size_t ws_size,
                              hipStream_t stream) {
    const int* es = (const int*)d_in[3];
    const int* ed = (const int*)d_in[4];

    char* wsb = (char*)d_ws;
    size_t off = 0;
    int*  flag    = (int*)wsb;               off = align256(off + sizeof(int));
    int*  M       = (int*)(wsb + off);       off = align256(off + (size_t)NB_HIST * NBUCKET * 4);
    int*  bbase   = (int*)(wsb + off);       off = align256(off + (size_t)(NBUCKET + 1) * 4);
    int*  tot     = (int*)(wsb + off);       off = align256(off + (size_t)NBUCKET * 4);
    int*  row_ptr = (int*)(wsb + off);       off = align256(off + (size_t)(N_NODES + 1) * 4);
    int2* sedge   = (int2*)(wsb + off);      off = align256(off + (size_t)N_EDGES * 8);
    size_t z_off = off;
    // aux (32 MB) aliases x0: bucket_csr consumes aux before init writes x0.
    int2* aux = (int2*)(wsb + z_off);

    const size_t bfbuf = (size_t)N_ELEM * sizeof(__hip_bfloat16); // 32 MB

    const int eb = 256;
    const int egrid = (N_ELEM / 4 + eb - 1) / eb;         // init, x4-vectorized
    const int sgrid = (N_NODES + 3) / 4;                  // 62500 blocks, 4 waves each
    const int wgrid = (NBUCKET + 3) / 4;                  // 1 wave per bucket kernels

    // ---- build: probe + deterministic two-pass binning (no global atomics) ----
    probe_dtype<<<1, 64, 0, stream>>>((const unsigned short*)d_in[0], flag);
    hist_bucket<<<NB_HIST, eb, 0, stream>>>(ed, M);
    col_sum<<<wgrid, eb, 0, stream>>>(M, tot);
    scan_bbase<<<1, 1024, 0, stream>>>(tot, bbase, row_ptr);
    row_base<<<wgrid, eb, 0, stream>>>(M, bbase);
    bin_scatter<<<NB_HIST, eb, 0, stream>>>(es, ed, d_in[2], flag, M, aux);
    bucket_csr<<<NBUCKET, eb, 0, stream>>>(bbase, aux, row_ptr, sedge);

    size_t need_t1 = z_off + 3 * bfbuf;   // ~137 MB

    if (ws_size >= need_t1) {
        // T1: bf16 x0,x1,x2; last spmm fuses the 4-term average into d_out
        __hip_bfloat16* x0 = (__hip_bfloat16*)(wsb + z_off);
        __hip_bfloat16* x1 = x0 + N_ELEM;
        __hip_bfloat16* x2 = x1 + N_ELEM;
        init_kernel<<<egrid, eb, 0, stream>>>(d_in[0], d_in[1], flag, x0, nullptr);
        spmm_csr<0><<<sgrid, eb, 0, stream>>>(row_ptr, sedge, x0, x1, nullptr, nullptr, nullptr, flag);
        spmm_csr<0><<<sgrid, eb, 0, stream>>>(row_ptr, sedge, x1, x2, nullptr, nullptr, nullptr, flag);
        spmm_csr<1><<<sgrid, eb, 0, stream>>>(row_ptr, sedge, x2, nullptr, x0, x1, d_out, flag);
    } else {
        // T2: bf16 x, xn; accumulate into d_out (RMW)
        __hip_bfloat16* x  = (__hip_bfloat16*)(wsb + z_off);
        __hip_bfloat16* xn = x + N_ELEM;
        init_kernel<<<egrid, eb, 0, stream>>>(d_in[0], d_in[1], flag, x, d_out);
        spmm_csr<2><<<sgrid, eb, 0, stream>>>(row_ptr, sedge, x,  xn, nullptr, nullptr, d_out, flag);
        spmm_csr<2><<<sgrid, eb, 0, stream>>>(row_ptr, sedge, xn, x,  nullptr, nullptr, d_out, flag);
        spmm_csr<3><<<sgrid, eb, 0, stream>>>(row_ptr, sedge, x,  nullptr, nullptr, nullptr, d_out, flag);
    }
}